// Round 4
// baseline (997.242 us; speedup 1.0000x reference)
//
#include <hip/hip_runtime.h>
#include <math.h>

#define B_SZ   256
#define D_IN   2048
#define HID    2048
#define NSEG   10
#define D_CTX  1024
#define OUT_N  100
#define KWIN   102
#define CAPS   96    // seg row nnz cap (mean 51.2, sigma 7.0; max over 41k rows ~84)
#define CAPF   160   // FF row nnz cap (mean 102.4, sigma 9.9; max over 4k rows ~145)
#define NCT    16    // batch cols per dendgate tile (16*1024*4B = 64 KB LDS)

typedef float f32x4 __attribute__((ext_vector_type(4)));

__device__ __forceinline__ f32x4 ntld4(const float* p) {
  return __builtin_nontemporal_load((const f32x4*)p);
}

// ---------- sortable-key helpers for exact fp32 top-k ----------
__device__ __forceinline__ unsigned f2key(float f) {
  unsigned b = __float_as_uint(f);
  return (b & 0x80000000u) ? ~b : (b | 0x80000000u);
}
__device__ __forceinline__ float key2f(unsigned k) {
  return (k & 0x80000000u) ? __uint_as_float(k & 0x7FFFFFFFu) : __uint_as_float(~k);
}

// ---------- combined transpose for x and ctx ----------
__global__ __launch_bounds__(256) void transpose2_k(const float* __restrict__ xsrc,
                                                    float* __restrict__ xdst,
                                                    const float* __restrict__ csrc,
                                                    float* __restrict__ cdst) {
  __shared__ float tile[32][33];
  int bid = blockIdx.x;
  const float* src; float* dst; int cols;
  const int NX = (D_IN / 32) * (B_SZ / 32);  // 512
  if (bid < NX) { src = xsrc; dst = xdst; cols = D_IN; }
  else { bid -= NX; src = csrc; dst = cdst; cols = D_CTX; }
  int nbx = cols / 32;
  int bx = bid % nbx, by = bid / nbx;
  int c0 = bx * 32, r0 = by * 32;
  int tx = threadIdx.x & 31, ty = threadIdx.x >> 5;
  for (int i = ty; i < 32; i += 8)
    tile[i][tx] = src[(r0 + i) * cols + (c0 + tx)];
  __syncthreads();
  for (int i = ty; i < 32; i += 8)
    dst[(c0 + i) * B_SZ + (r0 + tx)] = tile[tx][i];
}

// ---------- pass A: compact one masked row (all loads issued up front) ----------
template<int PER, int CAP>
__device__ __forceinline__ void compact_row(const float* __restrict__ w,
                                            const float* __restrict__ mk,
                                            float2* __restrict__ outP,
                                            int* __restrict__ outC,
                                            float2* buf, int* scnt) {
  const int t = threadIdx.x & 63;
  f32x4 wv[PER], mv[PER];
#pragma unroll
  for (int i = 0; i < PER; ++i) {
    wv[i] = ntld4(w + 4 * (t + 64 * i));
    mv[i] = ntld4(mk + 4 * (t + 64 * i));
  }
  if (t == 0) *scnt = 0;
  __builtin_amdgcn_wave_barrier();
#pragma unroll
  for (int i = 0; i < PER; ++i) {
    int e = t + 64 * i;
    f32x4 ww = wv[i], mm = mv[i];
    bool n0 = (mm.x != 0.f), n1 = (mm.y != 0.f), n2 = (mm.z != 0.f), n3 = (mm.w != 0.f);
    int nz = (int)n0 + (int)n1 + (int)n2 + (int)n3;
    if (nz) {
      int pos = atomicAdd(scnt, nz);
      int c = e << 2;
      if (n0) { if (pos < CAP) buf[pos] = make_float2(ww.x, __int_as_float(c));     pos++; }
      if (n1) { if (pos < CAP) buf[pos] = make_float2(ww.y, __int_as_float(c + 1)); pos++; }
      if (n2) { if (pos < CAP) buf[pos] = make_float2(ww.z, __int_as_float(c + 2)); pos++; }
      if (n3) { if (pos < CAP) buf[pos] = make_float2(ww.w, __int_as_float(c + 3)); pos++; }
    }
  }
  __builtin_amdgcn_wave_barrier();
  int c = *scnt;
  if (c > CAP) c = CAP;
  for (int i = t; i < c; i += 64) outP[i] = buf[i];
  if (t == 0) *outC = c;
}

// FF rows: rid<2048 -> W1/ff1P ; else W2/ff2P. grid 1024 blocks.
__global__ __launch_bounds__(256, 4) void compact_ff_k(
    const float* __restrict__ W1, const float* __restrict__ mW1,
    const float* __restrict__ W2, const float* __restrict__ mW2,
    float2* __restrict__ ff1P, int* __restrict__ ff1C,
    float2* __restrict__ ff2P, int* __restrict__ ff2C) {
  __shared__ float2 buf_s[4][CAPF];
  __shared__ int cnt_s[4];
  int wave = threadIdx.x >> 6;
  int rid = blockIdx.x * 4 + wave;
  if (rid < HID)
    compact_row<8, CAPF>(W1 + (size_t)rid * D_IN, mW1 + (size_t)rid * D_IN,
                         ff1P + (size_t)rid * CAPF, ff1C + rid, buf_s[wave], &cnt_s[wave]);
  else {
    int u = rid - HID;
    compact_row<8, CAPF>(W2 + (size_t)u * HID, mW2 + (size_t)u * HID,
                         ff2P + (size_t)u * CAPF, ff2C + u, buf_s[wave], &cnt_s[wave]);
  }
}

// SEG rows: rid 0..40959 flat over [layer][u][s]. grid 10240 blocks.
__global__ __launch_bounds__(256, 4) void compact_seg_k(
    const float* __restrict__ segW1, const float* __restrict__ mS1,
    const float* __restrict__ segW2, const float* __restrict__ mS2,
    float2* __restrict__ segP, int* __restrict__ segC) {
  __shared__ float2 buf_s[4][CAPS];
  __shared__ int cnt_s[4];
  int wave = threadIdx.x >> 6;
  int rid = blockIdx.x * 4 + wave;
  const float *w, *mk;
  if (rid < HID * NSEG) {
    w = segW1 + (size_t)rid * D_CTX;  mk = mS1 + (size_t)rid * D_CTX;
  } else {
    int loc = rid - HID * NSEG;
    w = segW2 + (size_t)loc * D_CTX;  mk = mS2 + (size_t)loc * D_CTX;
  }
  compact_row<4, CAPS>(w, mk, segP + (size_t)rid * CAPS, segC + rid,
                       buf_s[wave], &cnt_s[wave]);
}

// ---------- pass B: dendrite gates via LDS ctx tile ----------
// grid = 16 col-tiles x 32 row-chunks = 512 blocks. rowid = layer*2048+u (0..4095);
// its segs live at segP[(rowid*10+s)*CAPS] (layer*20480+u*10+s == rowid*10+s).
__global__ __launch_bounds__(256) void dendgate_k(
    const float2* __restrict__ segP, const int* __restrict__ segC,
    const float* __restrict__ ctxT, float* __restrict__ gateT) {
  __shared__ float ctx_lds[D_CTX * NCT];  // 64 KB
  const int tile = blockIdx.x & 15;
  const int chunk = blockIdx.x >> 4;
  const int b0 = tile * NCT;
  {
    int tt = threadIdx.x;
    int cq = (tt & 3) * 4;
    for (int r = tt >> 2; r < D_CTX; r += 64) {
      f32x4 v = *(const f32x4*)(ctxT + (size_t)r * B_SZ + b0 + cq);
      *(f32x4*)(&ctx_lds[r * NCT + cq]) = v;
    }
  }
  __syncthreads();
  const int wave = threadIdx.x >> 6;
  const int l = threadIdx.x & 63;
  const int c = l & 15, g = l >> 4;   // 16 cols x 4 pair-groups
  for (int k = 0; k < 32; ++k) {
    int rowid = chunk * 128 + wave * 32 + k;
    const float2* __restrict__ prow = segP + (size_t)rowid * NSEG * CAPS;
    const int* __restrict__ crow = segC + rowid * NSEG;
    int cnts[NSEG];
#pragma unroll
    for (int s = 0; s < NSEG; ++s) cnts[s] = crow[s];   // batched scalar loads
    float bestA = -1.f, chosen = 0.f;
#pragma unroll 1
    for (int s = 0; s < NSEG; ++s) {
      const float2* __restrict__ pr = prow + s * CAPS;
      int cnt = cnts[s];
      float d0 = 0.f, d1 = 0.f, d2 = 0.f, d3 = 0.f;
      int j = g;
      for (; j + 12 < cnt; j += 16) {
        float2 pa = pr[j], pb = pr[j + 4], pc = pr[j + 8], pd = pr[j + 12];
        d0 += ctx_lds[__float_as_int(pa.y) * NCT + c] * pa.x;
        d1 += ctx_lds[__float_as_int(pb.y) * NCT + c] * pb.x;
        d2 += ctx_lds[__float_as_int(pc.y) * NCT + c] * pc.x;
        d3 += ctx_lds[__float_as_int(pd.y) * NCT + c] * pd.x;
      }
      for (; j < cnt; j += 4) {
        float2 p = pr[j];
        d0 += ctx_lds[__float_as_int(p.y) * NCT + c] * p.x;
      }
      float d = (d0 + d1) + (d2 + d3);
      d += __shfl_xor(d, 16, 64);
      d += __shfl_xor(d, 32, 64);   // all lanes now hold full sum for col c
      float a = fabsf(d);
      if (a > bestA) { bestA = a; chosen = d; }  // strict > == first-occurrence argmax
    }
    float gate = 1.f / (1.f + expf(-chosen));
    if (l < NCT) gateT[(size_t)rowid * B_SZ + b0 + c] = gate;
  }
}

// ---------- FF gather (+bias, *gate): one wave per u; pairs precompacted ----------
__global__ __launch_bounds__(256, 4) void ffgate_k(
    const float2* __restrict__ P, const int* __restrict__ C,
    const float* __restrict__ srcT, const float* __restrict__ gate,
    const float* __restrict__ bias, float* __restrict__ yT) {
  int wave = threadIdx.x >> 6, t = threadIdx.x & 63, t4 = t * 4;
  int u = blockIdx.x * 4 + wave;
  const float2* __restrict__ pr = P + (size_t)u * CAPF;
  int cnt = C[u];
  float acc[4][4];
#pragma unroll
  for (int s = 0; s < 4; ++s)
#pragma unroll
    for (int i = 0; i < 4; ++i) acc[s][i] = 0.f;
  int j = 0;
  for (; j + 8 <= cnt; j += 8) {
#pragma unroll
    for (int s = 0; s < 8; ++s) {
      float2 p = pr[j + s];
      const f32x4 cv = *(const f32x4*)(srcT + ((size_t)__float_as_int(p.y) << 8) + t4);
      acc[s & 3][0] += cv.x * p.x; acc[s & 3][1] += cv.y * p.x;
      acc[s & 3][2] += cv.z * p.x; acc[s & 3][3] += cv.w * p.x;
    }
  }
  for (; j < cnt; ++j) {
    float2 p = pr[j];
    const f32x4 cv = *(const f32x4*)(srcT + ((size_t)__float_as_int(p.y) << 8) + t4);
    acc[0][0] += cv.x * p.x; acc[0][1] += cv.y * p.x;
    acc[0][2] += cv.z * p.x; acc[0][3] += cv.w * p.x;
  }
  float bb = bias[u];
  float4 g4 = *(const float4*)(gate + (size_t)u * B_SZ + t4);
  float4 o;
  o.x = ((acc[0][0] + acc[1][0]) + (acc[2][0] + acc[3][0]) + bb) * g4.x;
  o.y = ((acc[0][1] + acc[1][1]) + (acc[2][1] + acc[3][1]) + bb) * g4.y;
  o.z = ((acc[0][2] + acc[1][2]) + (acc[2][2] + acc[3][2]) + bb) * g4.z;
  o.w = ((acc[0][3] + acc[1][3]) + (acc[2][3] + acc[3][3]) + bb) * g4.w;
  *(float4*)(yT + (size_t)u * B_SZ + t4) = o;
}

// ---------- exact top-K per batch column of yT [HID][B]; stable index-order ties ----------
__global__ __launch_bounds__(256) void topk_kernel(const float* __restrict__ yT,
                                                   float* __restrict__ dst, int mode) {
  const int b = blockIdx.x, t = threadIdx.x;
  __shared__ int hist[256];
  __shared__ int sfx[256];
  __shared__ unsigned sPref;
  __shared__ int sRem;
  unsigned myk[8];
#pragma unroll
  for (int i = 0; i < 8; ++i)
    myk[i] = f2key(yT[(size_t)(t * 8 + i) * B_SZ + b]);
  unsigned pref = 0;
  int rem = KWIN;
  for (int shift = 24; shift >= 0; shift -= 8) {
    hist[t] = 0;
    __syncthreads();
    unsigned hiMask = (shift == 24) ? 0u : (0xFFFFFFFFu << (shift + 8));
#pragma unroll
    for (int i = 0; i < 8; ++i) {
      unsigned k = myk[i];
      if ((k & hiMask) == pref) atomicAdd(&hist[(k >> shift) & 255], 1);
    }
    __syncthreads();
    sfx[t] = hist[t];
    __syncthreads();
    for (int off = 1; off < 256; off <<= 1) {
      int add = (t + off < 256) ? sfx[t + off] : 0;
      __syncthreads();
      sfx[t] += add;
      __syncthreads();
    }
    int s_incl = sfx[t];
    int s_excl = (t == 255) ? 0 : sfx[t + 1];
    if (s_incl >= rem && s_excl < rem) {
      sPref = pref | (((unsigned)t) << shift);
      sRem = rem - s_excl;
    }
    __syncthreads();
    pref = sPref;
    rem = sRem;
    __syncthreads();
  }
  int eq = 0;
#pragma unroll
  for (int i = 0; i < 8; ++i) eq += (myk[i] == pref) ? 1 : 0;
  sfx[t] = eq;
  __syncthreads();
  for (int off = 1; off < 256; off <<= 1) {
    int add = (t >= off) ? sfx[t - off] : 0;
    __syncthreads();
    sfx[t] += add;
    __syncthreads();
  }
  int excl = sfx[t] - eq;
  int taken = 0;
#pragma unroll
  for (int i = 0; i < 8; ++i) {
    unsigned k = myk[i];
    bool keep;
    if (k > pref) keep = true;
    else if (k == pref) { keep = (excl + taken) < rem; taken++; }
    else keep = false;
    float f = keep ? key2f(k) : 0.f;
    int uu = t * 8 + i;
    if (mode == 0) dst[(size_t)uu * B_SZ + b] = f;
    else dst[(size_t)b * HID + uu] = f;
  }
}

// ---------- Dale output head ----------
__global__ __launch_bounds__(256) void out_kernel(
    const float* __restrict__ h2, const float* __restrict__ Wex, const float* __restrict__ Wix,
    const float* __restrict__ Wei, const float* __restrict__ bo, float* __restrict__ out) {
  const int b = blockIdx.x, t = threadIdx.x;
  __shared__ float hrow[HID];
  __shared__ float red[256];
  float part = 0.f;
#pragma unroll
  for (int i = 0; i < 8; ++i) {
    int u = t + 256 * i;
    float v = h2[(size_t)b * HID + u];
    hrow[u] = v;
    part += v * Wix[u];
  }
  red[t] = part;
  __syncthreads();
  for (int off = 128; off > 0; off >>= 1) {
    if (t < off) red[t] += red[t + off];
    __syncthreads();
  }
  float S = red[0];
  const int w = t >> 6, l = t & 63;
  for (int o = w; o < OUT_N; o += 4) {
    float acc = 0.f;
    const float* wr = Wex + (size_t)o * HID;
#pragma unroll
    for (int q = 0; q < HID / 64; ++q) acc += hrow[l + 64 * q] * wr[l + 64 * q];
    for (int off = 32; off > 0; off >>= 1) acc += __shfl_down(acc, off, 64);
    if (l == 0) out[(size_t)b * OUT_N + o] = acc - Wei[o] * S + bo[o];
  }
}

extern "C" void kernel_launch(void* const* d_in, const int* in_sizes, int n_in,
                              void* d_out, int out_size, void* d_ws, size_t ws_size,
                              hipStream_t stream) {
  const float* x      = (const float*)d_in[0];
  const float* ctx    = (const float*)d_in[1];
  const float* W1     = (const float*)d_in[2];
  const float* b1     = (const float*)d_in[3];
  const float* segW1  = (const float*)d_in[4];
  const float* maskW1 = (const float*)d_in[5];
  const float* maskS1 = (const float*)d_in[6];
  const float* W2     = (const float*)d_in[7];
  const float* b2     = (const float*)d_in[8];
  const float* segW2  = (const float*)d_in[9];
  const float* maskW2 = (const float*)d_in[10];
  const float* maskS2 = (const float*)d_in[11];
  const float* Wex    = (const float*)d_in[12];
  const float* Wix    = (const float*)d_in[13];
  const float* Wei    = (const float*)d_in[14];
  const float* bo     = (const float*)d_in[15];
  float* out = (float*)d_out;
  float* ws = (float*)d_ws;

  float*  xT    = ws;              // 524288
  float*  ctxT  = ws + 524288;     // 262144
  float*  y1T   = ws + 786432;     // 524288 (h1T in place after topk)
  float*  y2T   = ws + 1310720;    // 524288
  float*  h2    = ws + 1835008;    // 524288 (row-major)
  float*  gateT = ws + 2359296;    // 2*524288 = 1048576  [layer][u][b]
  float2* segP  = (float2*)(ws + 3407872);    // 40960*96 pairs = 7864320 floats
  float2* ff1P  = (float2*)(ws + 11272192);   // 2048*160 pairs = 655360 floats
  float2* ff2P  = (float2*)(ws + 11927552);   // 655360 floats
  int*    segC  = (int*)(ws + 12582912);      // 40960
  int*    ff1C  = (int*)(ws + 12623872);      // 2048
  int*    ff2C  = (int*)(ws + 12625920);      // 2048  -> total 12627968 floats ~50.5 MB

  transpose2_k<<<768, 256, 0, stream>>>(x, xT, ctx, ctxT);
  compact_seg_k<<<2 * HID * NSEG / 4, 256, 0, stream>>>(segW1, maskS1, segW2, maskS2,
                                                        segP, segC);
  dendgate_k<<<512, 256, 0, stream>>>(segP, segC, ctxT, gateT);
  compact_ff_k<<<2 * HID / 4, 256, 0, stream>>>(W1, maskW1, W2, maskW2,
                                                ff1P, ff1C, ff2P, ff2C);
  ffgate_k<<<HID / 4, 256, 0, stream>>>(ff1P, ff1C, xT, gateT, b1, y1T);
  topk_kernel<<<B_SZ, 256, 0, stream>>>(y1T, y1T, 0);                       // h1T in place
  ffgate_k<<<HID / 4, 256, 0, stream>>>(ff2P, ff2C, y1T, gateT + (size_t)HID * B_SZ, b2, y2T);
  topk_kernel<<<B_SZ, 256, 0, stream>>>(y2T, h2, 1);                        // h2 rows
  out_kernel<<<B_SZ, 256, 0, stream>>>(h2, Wex, Wix, Wei, bo, out);
}

// Round 5
// 734.371 us; speedup vs baseline: 1.3580x; 1.3580x over previous
//
#include <hip/hip_runtime.h>
#include <math.h>

#define B_SZ   256
#define D_IN   2048
#define HID    2048
#define NSEG   10
#define D_CTX  1024
#define OUT_N  100
#define KWIN   102
#define CAPS   96    // seg row nnz cap (mean 51.2, sigma 7.0)
#define CAPF   160   // FF row nnz cap (mean 102.4, sigma 9.9)
#define NCT    16    // batch cols per dendgate tile (16*1024*4B = 64 KB LDS)

typedef float f32x4 __attribute__((ext_vector_type(4)));

__device__ __forceinline__ f32x4 ntld4(const float* p) {
  return __builtin_nontemporal_load((const f32x4*)p);
}

// ---------- sortable-key helpers for exact fp32 top-k ----------
__device__ __forceinline__ unsigned f2key(float f) {
  unsigned b = __float_as_uint(f);
  return (b & 0x80000000u) ? ~b : (b | 0x80000000u);
}
__device__ __forceinline__ float key2f(unsigned k) {
  return (k & 0x80000000u) ? __uint_as_float(k & 0x7FFFFFFFu) : __uint_as_float(~k);
}

// ---------- combined transpose for x and ctx ----------
__global__ __launch_bounds__(256) void transpose2_k(const float* __restrict__ xsrc,
                                                    float* __restrict__ xdst,
                                                    const float* __restrict__ csrc,
                                                    float* __restrict__ cdst) {
  __shared__ float tile[32][33];
  int bid = blockIdx.x;
  const float* src; float* dst; int cols;
  const int NX = (D_IN / 32) * (B_SZ / 32);  // 512
  if (bid < NX) { src = xsrc; dst = xdst; cols = D_IN; }
  else { bid -= NX; src = csrc; dst = cdst; cols = D_CTX; }
  int nbx = cols / 32;
  int bx = bid % nbx, by = bid / nbx;
  int c0 = bx * 32, r0 = by * 32;
  int tx = threadIdx.x & 31, ty = threadIdx.x >> 5;
  for (int i = ty; i < 32; i += 8)
    tile[i][tx] = src[(r0 + i) * cols + (c0 + tx)];
  __syncthreads();
  for (int i = ty; i < 32; i += 8)
    dst[(c0 + i) * B_SZ + (r0 + tx)] = tile[tx][i];
}

// ---------- ballot-ordered compaction (deterministic index order, no LDS/atomics) ----------
template<int PER>
__device__ __forceinline__ void load_rowT(const float* __restrict__ w,
                                          const float* __restrict__ m,
                                          f32x4* wv, f32x4* mv) {
  const int t = threadIdx.x & 63;
#pragma unroll
  for (int i = 0; i < PER; ++i) {
    wv[i] = ntld4(w + 4 * (t + 64 * i));
    mv[i] = ntld4(m + 4 * (t + 64 * i));
  }
}

template<int PER>
__device__ __forceinline__ void emit_rowT(const f32x4* wv, const f32x4* mv,
                                          float2* __restrict__ outP, int cap,
                                          int* __restrict__ outC) {
  const int t = threadIdx.x & 63;
  const unsigned long long ltm = (1ull << t) - 1ull;
  int base = 0;
#pragma unroll
  for (int i = 0; i < PER; ++i) {
    f32x4 ww = wv[i], mm = mv[i];
    bool n0 = (mm.x != 0.f), n1 = (mm.y != 0.f), n2 = (mm.z != 0.f), n3 = (mm.w != 0.f);
    unsigned long long b0 = __ballot(n0), b1 = __ballot(n1);
    unsigned long long b2 = __ballot(n2), b3 = __ballot(n3);
    int pos = base + __popcll(b0 & ltm) + __popcll(b1 & ltm)
                   + __popcll(b2 & ltm) + __popcll(b3 & ltm);
    int e = (t + 64 * i) * 4;
    if (n0) { if (pos < cap) outP[pos] = make_float2(ww.x, __int_as_float(e));     pos++; }
    if (n1) { if (pos < cap) outP[pos] = make_float2(ww.y, __int_as_float(e + 1)); pos++; }
    if (n2) { if (pos < cap) outP[pos] = make_float2(ww.z, __int_as_float(e + 2)); pos++; }
    if (n3) { if (pos < cap) outP[pos] = make_float2(ww.w, __int_as_float(e + 3)); pos++; }
    base += __popcll(b0) + __popcll(b1) + __popcll(b2) + __popcll(b3);
  }
  if (t == 0) *outC = base > cap ? cap : base;
}

// seg compaction: 4 rows/wave (32 loads in flight)
__device__ __forceinline__ void compact_seg4(const float* __restrict__ segW,
                                             const float* __restrict__ mS,
                                             int r0 /*local seg row*/, int rbase /*global*/,
                                             float2* __restrict__ segP, int* __restrict__ segC) {
  f32x4 wv[16], mv[16];
#pragma unroll
  for (int q = 0; q < 4; ++q)
    load_rowT<4>(segW + (size_t)(r0 + q) * D_CTX, mS + (size_t)(r0 + q) * D_CTX,
                 wv + 4 * q, mv + 4 * q);
#pragma unroll
  for (int q = 0; q < 4; ++q)
    emit_rowT<4>(wv + 4 * q, mv + 4 * q,
                 segP + (size_t)(rbase + r0 + q) * CAPS, CAPS, segC + rbase + r0 + q);
}

// ff compaction: 2 rows/wave (32 loads in flight)
__device__ __forceinline__ void compact_ff2(const float* __restrict__ W,
                                            const float* __restrict__ mW,
                                            int u0 /*local*/, int fbase /*global*/,
                                            float2* __restrict__ ffP, int* __restrict__ ffC) {
  f32x4 wv[16], mv[16];
  load_rowT<8>(W + (size_t)u0 * HID, mW + (size_t)u0 * HID, wv, mv);
  load_rowT<8>(W + (size_t)(u0 + 1) * HID, mW + (size_t)(u0 + 1) * HID, wv + 8, mv + 8);
  emit_rowT<8>(wv, mv, ffP + (size_t)(fbase + u0) * CAPF, CAPF, ffC + fbase + u0);
  emit_rowT<8>(wv + 8, mv + 8, ffP + (size_t)(fbase + u0 + 1) * CAPF, CAPF, ffC + fbase + u0 + 1);
}

// ---------- dendgate: LDS ctx tile + shfl-broadcast pairs + ds_read_b128 ----------
// 64 lanes = 16 pair-groups (g) x 4 col-quads (cq). Bank swizzle p=(cq+r+(r>>2))&3
// spreads 16 random rows over all 8 (parity,quad) bank slots (~2-way avg: free).
__device__ __forceinline__ void dendgate_dev(
    const float2* __restrict__ segP, const int* __restrict__ segC,
    const float* __restrict__ ctxT, float* __restrict__ gateT,
    float* tile, int layer, int bid) {
  const int tileIdx = bid & 15;   // 16 col tiles
  const int chunk = bid >> 4;     // 64 chunks x 32 rows
  const int b0 = tileIdx * NCT;
  {
    const int t = threadIdx.x;
    const int rb = t >> 2, cq = t & 3;
#pragma unroll
    for (int j = 0; j < 16; ++j) {
      int r = rb + 64 * j;
      f32x4 v = *(const f32x4*)(ctxT + (size_t)r * B_SZ + b0 + cq * 4);
      int p = (cq + r + (r >> 2)) & 3;
      *(f32x4*)(tile + r * NCT + p * 4) = v;
    }
  }
  __syncthreads();
  const int wave = threadIdx.x >> 6;
  const int l = threadIdx.x & 63;
  const int g = l >> 2, cq = l & 3;
  for (int k = 0; k < 8; ++k) {
    const int rowid = layer * HID + chunk * 32 + wave * 8 + k;
    const float2* __restrict__ prow = segP + (size_t)rowid * NSEG * CAPS;
    int cn = (l < NSEG) ? segC[rowid * NSEG + l] : 0;
    int cnt = __shfl(cn, 0, 64);
    float pv0x = 0.f, pv0y = 0.f, pv1x = 0.f, pv1y = 0.f;
    if (l < cnt)      { float2 p = prow[l];      pv0x = p.x; pv0y = p.y; }
    if (l + 64 < cnt) { float2 p = prow[l + 64]; pv1x = p.x; pv1y = p.y; }
    float bestA[4] = {-1.f, -1.f, -1.f, -1.f};
    float chosen[4] = {0.f, 0.f, 0.f, 0.f};
    for (int s = 0; s < NSEG; ++s) {
      // prefetch next seg's pairs (vmcnt; independent of ds lgkmcnt below)
      int cntn = 0;
      float nv0x = 0.f, nv0y = 0.f, nv1x = 0.f, nv1y = 0.f;
      if (s + 1 < NSEG) {
        cntn = __shfl(cn, s + 1, 64);
        const float2* pn = prow + (s + 1) * CAPS;
        if (l < cntn)      { float2 p = pn[l];      nv0x = p.x; nv0y = p.y; }
        if (l + 64 < cntn) { float2 p = pn[l + 64]; nv1x = p.x; nv1y = p.y; }
      }
      float a0 = 0.f, a1 = 0.f, a2 = 0.f, a3 = 0.f;
      int steps = (cnt + 15) >> 4;
#pragma unroll 2
      for (int kk = 0; kk < steps; ++kk) {
        int j = kk * 16 + g;
        float vv, ri;
        if (kk < 4) { vv = __shfl(pv0x, j, 64);      ri = __shfl(pv0y, j, 64); }
        else        { vv = __shfl(pv1x, j - 64, 64); ri = __shfl(pv1y, j - 64, 64); }
        int r = __float_as_int(ri);
        int p = (cq + r + (r >> 2)) & 3;
        f32x4 cv = *(const f32x4*)(tile + r * NCT + p * 4);
        a0 += cv.x * vv; a1 += cv.y * vv; a2 += cv.z * vv; a3 += cv.w * vv;
      }
#pragma unroll
      for (int d = 4; d < 64; d <<= 1) {
        a0 += __shfl_xor(a0, d, 64); a1 += __shfl_xor(a1, d, 64);
        a2 += __shfl_xor(a2, d, 64); a3 += __shfl_xor(a3, d, 64);
      }
      float dd[4] = {a0, a1, a2, a3};
#pragma unroll
      for (int i = 0; i < 4; ++i) {
        float a = fabsf(dd[i]);
        if (a > bestA[i]) { bestA[i] = a; chosen[i] = dd[i]; }  // strict > == first occurrence
      }
      cnt = cntn; pv0x = nv0x; pv0y = nv0y; pv1x = nv1x; pv1y = nv1y;
    }
    if (g == 0) {
      f32x4 o;
      o.x = 1.f / (1.f + expf(-chosen[0]));
      o.y = 1.f / (1.f + expf(-chosen[1]));
      o.z = 1.f / (1.f + expf(-chosen[2]));
      o.w = 1.f / (1.f + expf(-chosen[3]));
      *(f32x4*)(gateT + (size_t)rowid * B_SZ + b0 + cq * 4) = o;
    }
  }
}

// ---------- FF gather via shfl-broadcast pairs (no LDS) ----------
__device__ __forceinline__ void gbank(float pvx, float pvy, int n,
                                      const float* __restrict__ srcT, int t4,
                                      float acc[4][4]) {
  int j = 0;
  for (; j + 4 <= n; j += 4) {
#pragma unroll
    for (int s = 0; s < 4; ++s) {
      float vv = __shfl(pvx, j + s, 64);
      float ri = __shfl(pvy, j + s, 64);
      const f32x4 cv = *(const f32x4*)(srcT + ((size_t)__float_as_int(ri) << 8) + t4);
      acc[s][0] += cv.x * vv; acc[s][1] += cv.y * vv;
      acc[s][2] += cv.z * vv; acc[s][3] += cv.w * vv;
    }
  }
  for (; j < n; ++j) {
    float vv = __shfl(pvx, j, 64);
    float ri = __shfl(pvy, j, 64);
    const f32x4 cv = *(const f32x4*)(srcT + ((size_t)__float_as_int(ri) << 8) + t4);
    acc[0][0] += cv.x * vv; acc[0][1] += cv.y * vv;
    acc[0][2] += cv.z * vv; acc[0][3] += cv.w * vv;
  }
}

__device__ __forceinline__ void ffgate_dev(
    const float2* __restrict__ ffP, const int* __restrict__ ffC, int frow,
    const float* __restrict__ srcT, const float* __restrict__ grow,
    float bb, float* __restrict__ yrow) {
  const int l = threadIdx.x & 63, t4 = l * 4;
  const float2* __restrict__ pr = ffP + (size_t)frow * CAPF;
  int cnt = ffC[frow];
  float p0x = 0.f, p0y = 0.f, p1x = 0.f, p1y = 0.f, p2x = 0.f, p2y = 0.f;
  if (l < cnt)       { float2 p = pr[l];       p0x = p.x; p0y = p.y; }
  if (l + 64 < cnt)  { float2 p = pr[l + 64];  p1x = p.x; p1y = p.y; }
  if (l + 128 < cnt) { float2 p = pr[l + 128]; p2x = p.x; p2y = p.y; }
  float acc[4][4];
#pragma unroll
  for (int s = 0; s < 4; ++s)
#pragma unroll
    for (int i = 0; i < 4; ++i) acc[s][i] = 0.f;
  int n0 = cnt > 64 ? 64 : cnt;
  gbank(p0x, p0y, n0, srcT, t4, acc);
  if (cnt > 64)  gbank(p1x, p1y, (cnt - 64 > 64 ? 64 : cnt - 64), srcT, t4, acc);
  if (cnt > 128) gbank(p2x, p2y, cnt - 128, srcT, t4, acc);
  f32x4 g4 = *(const f32x4*)(grow + t4);
  f32x4 o;
  o.x = ((acc[0][0] + acc[1][0]) + (acc[2][0] + acc[3][0]) + bb) * g4.x;
  o.y = ((acc[0][1] + acc[1][1]) + (acc[2][1] + acc[3][1]) + bb) * g4.y;
  o.z = ((acc[0][2] + acc[1][2]) + (acc[2][2] + acc[3][2]) + bb) * g4.z;
  o.w = ((acc[0][3] + acc[1][3]) + (acc[2][3] + acc[3][3]) + bb) * g4.w;
  *(f32x4*)(yrow + t4) = o;
}

// ---------- K2: compact all layer-1 weights ----------
__global__ __launch_bounds__(256, 2) void compact1_k(
    const float* __restrict__ W1, const float* __restrict__ mW1,
    const float* __restrict__ segW1, const float* __restrict__ mS1,
    float2* __restrict__ ffP, int* __restrict__ ffC,
    float2* __restrict__ segP, int* __restrict__ segC) {
  const int wave = threadIdx.x >> 6;
  const int bid = blockIdx.x;
  if (bid < 256) {
    int u0 = (bid * 4 + wave) * 2;                 // [0,2048)
    // layer-1 FF rows have D_IN=2048 columns (same as HID)
    compact_ff2(W1, mW1, u0, 0, ffP, ffC);
  } else {
    int r0 = ((bid - 256) * 4 + wave) * 4;         // [0,20480)
    compact_seg4(segW1, mS1, r0, 0, segP, segC);
  }
}

// ---------- K3: dendgate layer-1  ||  compact layer-2 ----------
__global__ __launch_bounds__(256, 2) void k3_mix(
    const float* __restrict__ W2, const float* __restrict__ mW2,
    const float* __restrict__ segW2, const float* __restrict__ mS2,
    float2* __restrict__ ffP, int* __restrict__ ffC,
    float2* __restrict__ segP, int* __restrict__ segC,
    const float* __restrict__ ctxT, float* __restrict__ gateT) {
  __shared__ float tile[D_CTX * NCT];
  const int bid = blockIdx.x;
  const int wave = threadIdx.x >> 6;
  if (bid < 1024) {
    dendgate_dev(segP, segC, ctxT, gateT, tile, 0, bid);
  } else if (bid < 1280) {
    int u0 = ((bid - 1024) * 4 + wave) * 2;        // [0,2048)
    compact_ff2(W2, mW2, u0, HID, ffP, ffC);       // ff rows 2048..4095
  } else {
    int r0 = ((bid - 1280) * 4 + wave) * 4;        // [0,20480)
    compact_seg4(segW2, mS2, r0, HID * NSEG, segP, segC);  // seg rows 20480..40959
  }
}

// ---------- K4: dendgate layer-2  ||  ffgate layer-1 ----------
__global__ __launch_bounds__(256, 2) void k4_mix(
    const float2* __restrict__ segP, const int* __restrict__ segC,
    const float* __restrict__ ctxT, float* __restrict__ gateT,
    const float2* __restrict__ ffP, const int* __restrict__ ffC,
    const float* __restrict__ xT, const float* __restrict__ b1,
    float* __restrict__ y1T) {
  __shared__ float tile[D_CTX * NCT];
  const int bid = blockIdx.x;
  if (bid < 1024) {
    dendgate_dev(segP, segC, ctxT, gateT, tile, 1, bid);
  } else {
    int u = (bid - 1024) * 4 + (threadIdx.x >> 6);  // [0,2048)
    ffgate_dev(ffP, ffC, u, xT, gateT + (size_t)u * B_SZ, b1[u],
               y1T + (size_t)u * B_SZ);
  }
}

// ---------- K6: ffgate layer-2 ----------
__global__ __launch_bounds__(256, 4) void ffgate2_k(
    const float2* __restrict__ ffP, const int* __restrict__ ffC,
    const float* __restrict__ h1T, const float* __restrict__ gateT,
    const float* __restrict__ b2, float* __restrict__ y2T) {
  int u = blockIdx.x * 4 + (threadIdx.x >> 6);
  ffgate_dev(ffP, ffC, HID + u, h1T, gateT + (size_t)(HID + u) * B_SZ, b2[u],
             y2T + (size_t)u * B_SZ);
}

// ---------- exact top-K per batch column of yT [HID][B]; stable index-order ties ----------
__global__ __launch_bounds__(256) void topk_kernel(const float* __restrict__ yT,
                                                   float* __restrict__ dst, int mode) {
  const int b = blockIdx.x, t = threadIdx.x;
  __shared__ int hist[256];
  __shared__ int sfx[256];
  __shared__ unsigned sPref;
  __shared__ int sRem;
  unsigned myk[8];
#pragma unroll
  for (int i = 0; i < 8; ++i)
    myk[i] = f2key(yT[(size_t)(t * 8 + i) * B_SZ + b]);
  unsigned pref = 0;
  int rem = KWIN;
  for (int shift = 24; shift >= 0; shift -= 8) {
    hist[t] = 0;
    __syncthreads();
    unsigned hiMask = (shift == 24) ? 0u : (0xFFFFFFFFu << (shift + 8));
#pragma unroll
    for (int i = 0; i < 8; ++i) {
      unsigned k = myk[i];
      if ((k & hiMask) == pref) atomicAdd(&hist[(k >> shift) & 255], 1);
    }
    __syncthreads();
    sfx[t] = hist[t];
    __syncthreads();
    for (int off = 1; off < 256; off <<= 1) {
      int add = (t + off < 256) ? sfx[t + off] : 0;
      __syncthreads();
      sfx[t] += add;
      __syncthreads();
    }
    int s_incl = sfx[t];
    int s_excl = (t == 255) ? 0 : sfx[t + 1];
    if (s_incl >= rem && s_excl < rem) {
      sPref = pref | (((unsigned)t) << shift);
      sRem = rem - s_excl;
    }
    __syncthreads();
    pref = sPref;
    rem = sRem;
    __syncthreads();
  }
  int eq = 0;
#pragma unroll
  for (int i = 0; i < 8; ++i) eq += (myk[i] == pref) ? 1 : 0;
  sfx[t] = eq;
  __syncthreads();
  for (int off = 1; off < 256; off <<= 1) {
    int add = (t >= off) ? sfx[t - off] : 0;
    __syncthreads();
    sfx[t] += add;
    __syncthreads();
  }
  int excl = sfx[t] - eq;
  int taken = 0;
#pragma unroll
  for (int i = 0; i < 8; ++i) {
    unsigned k = myk[i];
    bool keep;
    if (k > pref) keep = true;
    else if (k == pref) { keep = (excl + taken) < rem; taken++; }
    else keep = false;
    float f = keep ? key2f(k) : 0.f;
    int uu = t * 8 + i;
    if (mode == 0) dst[(size_t)uu * B_SZ + b] = f;
    else dst[(size_t)b * HID + uu] = f;
  }
}

// ---------- Dale output head ----------
__global__ __launch_bounds__(256) void out_kernel(
    const float* __restrict__ h2, const float* __restrict__ Wex, const float* __restrict__ Wix,
    const float* __restrict__ Wei, const float* __restrict__ bo, float* __restrict__ out) {
  const int b = blockIdx.x, t = threadIdx.x;
  __shared__ float hrow[HID];
  __shared__ float red[256];
  float part = 0.f;
#pragma unroll
  for (int i = 0; i < 8; ++i) {
    int u = t + 256 * i;
    float v = h2[(size_t)b * HID + u];
    hrow[u] = v;
    part += v * Wix[u];
  }
  red[t] = part;
  __syncthreads();
  for (int off = 128; off > 0; off >>= 1) {
    if (t < off) red[t] += red[t + off];
    __syncthreads();
  }
  float S = red[0];
  const int w = t >> 6, l = t & 63;
  for (int o = w; o < OUT_N; o += 4) {
    float acc = 0.f;
    const float* wr = Wex + (size_t)o * HID;
#pragma unroll
    for (int q = 0; q < HID / 64; ++q) acc += hrow[l + 64 * q] * wr[l + 64 * q];
    for (int off = 32; off > 0; off >>= 1) acc += __shfl_down(acc, off, 64);
    if (l == 0) out[(size_t)b * OUT_N + o] = acc - Wei[o] * S + bo[o];
  }
}

extern "C" void kernel_launch(void* const* d_in, const int* in_sizes, int n_in,
                              void* d_out, int out_size, void* d_ws, size_t ws_size,
                              hipStream_t stream) {
  const float* x      = (const float*)d_in[0];
  const float* ctx    = (const float*)d_in[1];
  const float* W1     = (const float*)d_in[2];
  const float* b1     = (const float*)d_in[3];
  const float* segW1  = (const float*)d_in[4];
  const float* maskW1 = (const float*)d_in[5];
  const float* maskS1 = (const float*)d_in[6];
  const float* W2     = (const float*)d_in[7];
  const float* b2     = (const float*)d_in[8];
  const float* segW2  = (const float*)d_in[9];
  const float* maskW2 = (const float*)d_in[10];
  const float* maskS2 = (const float*)d_in[11];
  const float* Wex    = (const float*)d_in[12];
  const float* Wix    = (const float*)d_in[13];
  const float* Wei    = (const float*)d_in[14];
  const float* bo     = (const float*)d_in[15];
  float* out = (float*)d_out;
  float* ws = (float*)d_ws;

  float*  xT    = ws;              // 524288
  float*  ctxT  = ws + 524288;     // 262144
  float*  y1T   = ws + 786432;     // 524288 (h1T in place after topk)
  float*  y2T   = ws + 1310720;    // 524288
  float*  h2    = ws + 1835008;    // 524288 (row-major)
  float*  gateT = ws + 2359296;    // 1048576  [layer*2048+u][b]
  float2* segP  = (float2*)(ws + 3407872);    // 40960*96 pairs
  float2* ffP   = (float2*)(ws + 11272192);   // 4096*160 pairs
  int*    segC  = (int*)(ws + 12582912);      // 40960
  int*    ffC   = (int*)(ws + 12623872);      // 4096  -> ~50.5 MB total

  transpose2_k<<<768, 256, 0, stream>>>(x, xT, ctx, ctxT);
  compact1_k<<<1536, 256, 0, stream>>>(W1, maskW1, segW1, maskS1, ffP, ffC, segP, segC);
  k3_mix<<<2560, 256, 0, stream>>>(W2, maskW2, segW2, maskS2, ffP, ffC, segP, segC,
                                   ctxT, gateT);
  k4_mix<<<1536, 256, 0, stream>>>(segP, segC, ctxT, gateT, ffP, ffC, xT, b1, y1T);
  topk_kernel<<<B_SZ, 256, 0, stream>>>(y1T, y1T, 0);   // h1T in place
  ffgate2_k<<<512, 256, 0, stream>>>(ffP, ffC, y1T, gateT, b2, y2T);
  topk_kernel<<<B_SZ, 256, 0, stream>>>(y2T, h2, 1);    // h2 rows
  out_kernel<<<B_SZ, 256, 0, stream>>>(h2, Wex, Wix, Wei, bo, out);
}